// Round 7
// baseline (3578.857 us; speedup 1.0000x reference)
//
#include <hip/hip_runtime.h>
#include <math.h>

#define NTOT 262144
#define BROWS 128
#define THREADS 512

typedef short bf16x8 __attribute__((ext_vector_type(8)));
typedef float f32x16 __attribute__((ext_vector_type(16)));

// ws u16 offsets (pre-split transposed weights Wt[n][k], k contiguous)
#define O0H 0
#define O0L 8192
#define O1H 16384
#define O1L 81920
#define O2H 147456
#define O2L 212992
// total 278528 u16 = 557056 B in d_ws

__device__ __forceinline__ unsigned short bf16_rne(float x){
    unsigned u = __float_as_uint(x);
    return (unsigned short)((u + 0x7FFFu + ((u >> 16) & 1u)) >> 16);
}
__device__ __forceinline__ void split2(float x, unsigned short& h, unsigned short& l){
    h = bf16_rne(x);
    float xh = __uint_as_float(((unsigned)h) << 16);
    l = bf16_rne(x - xh);
}

__global__ void prep_weights(const float* __restrict__ W0, const float* __restrict__ W1,
                             const float* __restrict__ W2, unsigned short* __restrict__ ws){
    int i = blockIdx.x * 256 + threadIdx.x;
    float v; int oh, ol;
    if (i < 8192){        int n = i >> 6, k = i & 63;                 v = W0[k*128 + n]; oh = O0H + i; ol = O0L + i; }
    else if (i < 73728){  int j = i - 8192;  int n = j >> 7, k = j & 127; v = W1[k*512 + n]; oh = O1H + j; ol = O1L + j; }
    else if (i < 139264){ int j = i - 73728; int n = j >> 9, k = j & 511; v = W2[k*128 + n]; oh = O2H + j; ol = O2L + j; }
    else return;
    unsigned short h, l; split2(v, h, l);
    ws[oh] = h; ws[ol] = l;
}

__device__ __forceinline__ void epilogue_row(const float* __restrict__ h, float r0v, float r1v,
        float& z0o, float& z1o, float& lseo, float& wLo, float& u0o, bool& lamo){
    float wraw[9]; float wsum = 0.0f;
    #pragma unroll
    for (int j = 0; j < 9; ++j){ wraw[j] = fabsf(h[32 + j]); wsum += wraw[j]; }
    float wL = wraw[8] / wsum;
    const bool lambert = r0v < wL;
    float u0 = lambert ? (r0v / wL) : ((r0v - wL) / (1.0f - wL));
    float U1 = lambert ? 0.5f : u0;
    U1 = fmaxf(U1, 1e-12f);
    float R  = sqrtf(-2.0f * logf(U1));
    float th = 6.28318530717958647692f * r1v;
    float ce = cosf(th), se = sinf(th);
    float es0[8], es1[8];
    float ssum0 = 0.0f, ssum1 = 0.0f, lsum0 = 0.0f, lsum1 = 0.0f;
    #pragma unroll
    for (int m = 0; m < 8; ++m){
        es0[m] = expf(h[16 + 2*m]); es1[m] = expf(h[16 + 2*m + 1]);
        ssum0 += es0[m]; ssum1 += es1[m];
        lsum0 += h[2*m]; lsum1 += h[2*m + 1];
    }
    float zg0 = (R * ce) * ssum0 + lsum0;
    float zg1 = (R * se) * ssum1 + lsum1;
    float wo0 = u0 * 2.0f - 1.0f;
    float wo1 = r1v * 2.0f - 1.0f;
    bool nonzero = !((wo0 == 0.0f) && (wo1 == 0.0f));
    bool c1 = (fabsf(wo0) > fabsf(wo1)) && nonzero;
    bool c2 = (!c1) && nonzero;
    float sa0 = (wo0 == 0.0f) ? 1.0f : wo0;
    float sa1 = (wo1 == 0.0f) ? 1.0f : wo1;
    float phi = c1 ? (0.78539816339f * wo1 / sa0)
                   : (1.57079632679f - 0.78539816339f * wo0 / sa1);
    float rr = c1 ? wo0 : (c2 ? wo1 : 0.0f);
    float zl0 = rr * cosf(phi);
    float zl1 = rr * sinf(phi);
    float z0 = lambert ? zl0 : zg0;
    float z1 = lambert ? zl1 : zg1;
    float lp[9];
    #pragma unroll
    for (int m = 0; m < 8; ++m){
        float e0 = (z0 - h[2*m])     / es0[m];
        float e1 = (z1 - h[2*m + 1]) / es1[m];
        float wm = wraw[m] / wsum;
        lp[m] = (-1.83787706640934548356f + logf(wm + 1e-5f))
                - 0.5f * (e0*e0 + e1*e1)
                - (h[16 + 2*m] + h[16 + 2*m + 1]);
    }
    float pdf = (z0*z0 + z1*z1 > 1.0f) ? 0.0f : 0.31830988618f;
    lp[8] = logf(pdf + 1e-5f) + logf(wL);
    float mx = lp[0];
    #pragma unroll
    for (int j = 1; j < 9; ++j) mx = fmaxf(mx, lp[j]);
    float s = 0.0f;
    #pragma unroll
    for (int j = 0; j < 9; ++j) s += expf(lp[j] - mx);
    z0o = z0; z1o = z1; lseo = mx + logf(s); wLo = wL; u0o = u0; lamo = lambert;
}

__device__ __forceinline__ f32x16 bias_init(const float* __restrict__ b, int mt, int lane, int nmax){
    f32x16 c;
    const int hq = ((lane >> 5) << 2);
    #pragma unroll
    for (int r = 0; r < 16; ++r){
        int n = mt + (r & 3) + ((r >> 2) << 3) + hq;
        c[r] = (n < nmax) ? b[n] : 0.0f;
    }
    return c;
}

// writes one 32x32 C tile (D[n][brow]) into act[brow][n] as split bf16, packed 8B runs
__device__ __forceinline__ void write_tile(unsigned short* __restrict__ ah, unsigned short* __restrict__ al,
        int pitch, int brow, int m0, int lane, const f32x16 acc, bool relu){
    const int hq = ((lane >> 5) << 2);
    #pragma unroll
    for (int q = 0; q < 4; ++q){
        ushort4 vh, vl;
        #pragma unroll
        for (int r = 0; r < 4; ++r){
            float x = acc[q*4 + r];
            if (relu) x = fmaxf(x, 0.0f);
            unsigned short hh, ll; split2(x, hh, ll);
            (&vh.x)[r] = hh; (&vl.x)[r] = ll;
        }
        const int off = brow*pitch + m0 + q*8 + hq;
        *(ushort4*)(ah + off) = vh;
        *(ushort4*)(al + off) = vl;
    }
}

// writes one 32x32 C tile into f32 transposed dst[n*128 + brow], with relu
__device__ __forceinline__ void write_tile_f32t(float* __restrict__ dst,
        int brow, int m0, int lane, const f32x16 acc){
    const int hq = ((lane >> 5) << 2);
    #pragma unroll
    for (int q = 0; q < 4; ++q){
        #pragma unroll
        for (int r = 0; r < 4; ++r){
            int n = m0 + q*8 + hq + r;
            dst[n*128 + brow] = fmaxf(acc[q*4 + r], 0.0f);
        }
    }
}

// D = Wt . act over NK k-steps of 16; Wt row pitch KP; act pitch given; T column tiles
template<int NK, int KP, int T>
__device__ __forceinline__ void gemm_phase(
        const unsigned short* __restrict__ wth, const unsigned short* __restrict__ wtl,
        const unsigned short* __restrict__ acth, const unsigned short* __restrict__ actl,
        int pitch, int brow, int m0, int lane, f32x16* acc){
    const int kl = ((lane >> 5) << 3);
    const int ml = lane & 31;
    #pragma unroll
    for (int ks = 0; ks < NK; ++ks){
        const int k0 = ks*16 + kl;
        bf16x8 ah = *(const bf16x8*)(acth + brow*pitch + k0);
        bf16x8 al = *(const bf16x8*)(actl + brow*pitch + k0);
        #pragma unroll
        for (int t = 0; t < T; ++t){
            const size_t wo = (size_t)(m0 + t*32 + ml) * KP + k0;
            bf16x8 wh = *(const bf16x8*)(wth + wo);
            bf16x8 wl = *(const bf16x8*)(wtl + wo);
            acc[t] = __builtin_amdgcn_mfma_f32_32x32x16_bf16(wh, ah, acc[t], 0, 0, 0);
            acc[t] = __builtin_amdgcn_mfma_f32_32x32x16_bf16(wh, al, acc[t], 0, 0, 0);
            acc[t] = __builtin_amdgcn_mfma_f32_32x32x16_bf16(wl, ah, acc[t], 0, 0, 0);
        }
    }
}

__global__ __launch_bounds__(THREADS, 1)
void gmm_mfma(const float* __restrict__ cond, const float* __restrict__ rnd,
              const unsigned short* __restrict__ ws,
              const float* __restrict__ W0, const float* __restrict__ b0,
              const float* __restrict__ W1, const float* __restrict__ b1,
              const float* __restrict__ W2, const float* __restrict__ b2,
              const float* __restrict__ W3, const float* __restrict__ b3,
              const float* __restrict__ W4, const float* __restrict__ b4,
              float* __restrict__ out)
{
    extern __shared__ unsigned char smem[];
    unsigned short* aAh = (unsigned short*)smem;         // [128][136] split h0
    unsigned short* aAl = aAh + 128*136;
    unsigned short* aBh = aAl + 128*136;                 // [128][136] split h1 chunk
    unsigned short* aBl = aBh + 128*136;
    float* h2f = (float*)smem;                           // [128 n][128 row] overlays aA after use
    float* h3f = (float*)(smem + 69632);                 // [32 n][128 row] overlays aB
    float* h4f = (float*)(smem + 86016);                 // [44 n][128 row]
    int* s_cnt  = (int*)(smem + 139264);
    int* s_rows = (int*)(smem + 139268);                 // 128 ints
    float* fb = (float*)smem;                            // fallback scratch (overlays h2f)

    const int tid  = threadIdx.x;
    const int lane = tid & 63;
    const int wv   = tid >> 6;
    const int row0 = blockIdx.x * BROWS;
    const int rg   = wv & 3;
    const int ctp  = wv >> 2;            // 0/1
    const int brow = rg*32 + (lane & 31);
    const int m0   = ctp * 64;
    const int kl   = ((lane >> 5) << 3);
    const int ml   = lane & 31;

    // ---- L0: h0 = relu(cond @ W0), B-frags straight from global cond ----
    {
        f32x16 acc0 = bias_init(b0, m0,      lane, 128);
        f32x16 acc1 = bias_init(b0, m0 + 32, lane, 128);
        #pragma unroll
        for (int ks = 0; ks < 4; ++ks){
            const int k0 = ks*16 + kl;
            const float* cp = cond + (size_t)(row0 + brow)*64 + k0;
            float4 ca = *(const float4*)cp;
            float4 cb = *(const float4*)(cp + 4);
            float xs[8] = {ca.x, ca.y, ca.z, ca.w, cb.x, cb.y, cb.z, cb.w};
            bf16x8 ah, al;
            #pragma unroll
            for (int j = 0; j < 8; ++j){
                unsigned short hh, ll; split2(xs[j], hh, ll);
                ah[j] = (short)hh; al[j] = (short)ll;
            }
            #pragma unroll
            for (int t = 0; t < 2; ++t){
                const size_t wo = (size_t)(m0 + t*32 + ml) * 64 + k0;
                bf16x8 wh = *(const bf16x8*)(ws + O0H + wo);
                bf16x8 wl = *(const bf16x8*)(ws + O0L + wo);
                f32x16& a = t ? acc1 : acc0;
                a = __builtin_amdgcn_mfma_f32_32x32x16_bf16(wh, ah, a, 0, 0, 0);
                a = __builtin_amdgcn_mfma_f32_32x32x16_bf16(wh, al, a, 0, 0, 0);
                a = __builtin_amdgcn_mfma_f32_32x32x16_bf16(wl, ah, a, 0, 0, 0);
            }
        }
        write_tile(aAh, aAl, 136, brow, m0,      lane, acc0, true);
        write_tile(aAh, aAl, 136, brow, m0 + 32, lane, acc1, true);
    }
    __syncthreads();

    // ---- L1 (chunked 128 cols) fused with L2 accumulation ----
    f32x16 acc2[2] = { bias_init(b2, m0, lane, 128), bias_init(b2, m0 + 32, lane, 128) };
    for (int c = 0; c < 4; ++c){
        f32x16 a1[2] = { bias_init(b1 + c*128, m0, lane, 512), bias_init(b1 + c*128, m0 + 32, lane, 512) };
        gemm_phase<8, 128, 2>(ws + O1H + (size_t)(c*128)*128, ws + O1L + (size_t)(c*128)*128,
                              aAh, aAl, 136, brow, m0, lane, a1);
        __syncthreads();   // prior L2 chunk reads of aB complete
        write_tile(aBh, aBl, 136, brow, m0,      lane, a1[0], true);
        write_tile(aBh, aBl, 136, brow, m0 + 32, lane, a1[1], true);
        __syncthreads();   // chunk acts visible
        gemm_phase<8, 512, 2>(ws + O2H + c*128, ws + O2L + c*128,
                              aBh, aBl, 136, brow, m0, lane, acc2);
    }
    // all aA reads finished before chunk-3's first barrier; write h2 (f32, transposed)
    write_tile_f32t(h2f, brow, m0,      lane, acc2[0]);
    write_tile_f32t(h2f, brow, m0 + 32, lane, acc2[1]);
    __syncthreads();       // h2 visible; all aB reads complete

    // ---- L3: 128 -> 32 relu, exact fp32 on VALU ----
    {
        const int row = tid & 127;
        const int nb  = __builtin_amdgcn_readfirstlane(tid >> 7);  // wave-uniform
        float acc[8];
        #pragma unroll
        for (int c = 0; c < 8; ++c) acc[c] = b3[nb*8 + c];
        #pragma unroll 4
        for (int k = 0; k < 128; ++k){
            float a = h2f[k*128 + row];
            const float* wr = W3 + k*32 + nb*8;
            #pragma unroll
            for (int c = 0; c < 8; ++c) acc[c] = fmaf(a, wr[c], acc[c]);
        }
        __syncthreads();
        #pragma unroll
        for (int c = 0; c < 8; ++c) h3f[(nb*8 + c)*128 + row] = fmaxf(acc[c], 0.0f);
    }
    if (tid == 0) *s_cnt = 0;
    __syncthreads();       // h3 visible

    // ---- L4: 32 -> 41, exact fp32 ----
    {
        const int row = tid & 127;
        const int nb  = __builtin_amdgcn_readfirstlane(tid >> 7);
        float acc[11];
        #pragma unroll
        for (int c = 0; c < 11; ++c){ int n = nb*11 + c; acc[c] = (n < 41) ? b4[n] : 0.0f; }
        #pragma unroll 4
        for (int k = 0; k < 32; ++k){
            float a = h3f[k*128 + row];
            const float* wr = W4 + k*41;
            #pragma unroll
            for (int c = 0; c < 11; ++c){ int n = nb*11 + c; if (n < 41) acc[c] = fmaf(a, wr[n], acc[c]); }
        }
        #pragma unroll
        for (int c = 0; c < 11; ++c){ int n = nb*11 + c; if (n < 41) h4f[n*128 + row] = acc[c]; }
    }
    __syncthreads();       // h4 visible

    // ---- epilogue (approx h) + sensitivity flags ----
    if (tid < 128){
        const int row  = tid;
        const int grow = row0 + row;
        float h[41];
        #pragma unroll
        for (int j = 0; j < 41; ++j) h[j] = h4f[j*128 + row];
        float2 rv = *(const float2*)(rnd + 2*(size_t)grow);
        float z0, z1, lse, wL, u0; bool lam;
        epilogue_row(h, rv.x, rv.y, z0, z1, lse, wL, u0, lam);
        ((float2*)out)[grow] = make_float2(z0, z1);
        out[(size_t)2*NTOT + grow] = lse;
        // flags: mask boundary; tiny wL (log(wL) rel-err blowup); large wL (u0 amplification);
        // pdf circle bands; extreme gauss u0.
        bool flag = (fabsf(rv.x - wL) < 5e-3f)
                 || (wL < 3e-3f) || (wL > 0.5f)
                 || (fabsf(z0*z0 + z1*z1 - 1.0f) < (lam ? 0.02f : 0.2f))
                 || (!lam && u0 < 3e-3f);
        if (flag){ int idx = atomicAdd(s_cnt, 1); s_rows[idx] = row; }
    }
    __syncthreads();
    const int cnt = *s_cnt;

    // ---- exact fp32 fallback for flagged rows (block-cooperative) ----
    float* c0f = fb;            // 64
    float* f0  = fb + 64;       // 128
    float* f1  = fb + 192;      // 512
    float* f2  = fb + 704;      // 128
    float* f3  = fb + 832;      // 32
    float* h4e = fb + 864;      // 41
    for (int i = 0; i < cnt; ++i){
        const int row  = s_rows[i];
        const int grow = row0 + row;
        if (tid < 64) c0f[tid] = cond[(size_t)grow*64 + tid];
        __syncthreads();
        if (tid < 128){
            float s0 = b0[tid], s1 = 0.0f;
            for (int k = 0; k < 64; k += 2){
                s0 = fmaf(c0f[k],   W0[k*128 + tid],     s0);
                s1 = fmaf(c0f[k+1], W0[(k+1)*128 + tid], s1);
            }
            f0[tid] = fmaxf(s0 + s1, 0.0f);
        }
        __syncthreads();
        {
            float s0 = b1[tid], s1 = 0.0f;
            for (int k = 0; k < 128; k += 2){
                s0 = fmaf(f0[k],   W1[k*512 + tid],     s0);
                s1 = fmaf(f0[k+1], W1[(k+1)*512 + tid], s1);
            }
            f1[tid] = fmaxf(s0 + s1, 0.0f);
        }
        __syncthreads();
        if (tid < 128){
            float s0 = b2[tid], s1 = 0.0f, s2 = 0.0f, s3 = 0.0f;
            for (int k = 0; k < 512; k += 4){
                s0 = fmaf(f1[k],   W2[k*128 + tid],     s0);
                s1 = fmaf(f1[k+1], W2[(k+1)*128 + tid], s1);
                s2 = fmaf(f1[k+2], W2[(k+2)*128 + tid], s2);
                s3 = fmaf(f1[k+3], W2[(k+3)*128 + tid], s3);
            }
            f2[tid] = fmaxf(((s0 + s1) + (s2 + s3)), 0.0f);
        }
        __syncthreads();
        if (tid < 32){
            float s0 = b3[tid], s1 = 0.0f;
            for (int k = 0; k < 128; k += 2){
                s0 = fmaf(f2[k],   W3[k*32 + tid],     s0);
                s1 = fmaf(f2[k+1], W3[(k+1)*32 + tid], s1);
            }
            f3[tid] = fmaxf(s0 + s1, 0.0f);
        }
        __syncthreads();
        if (tid < 41){
            float s = b4[tid];
            for (int k = 0; k < 32; ++k) s = fmaf(f3[k], W4[k*41 + tid], s);
            h4e[tid] = s;
        }
        __syncthreads();
        if (tid == 0){
            float2 rv = *(const float2*)(rnd + 2*(size_t)grow);
            float z0, z1, lse, wL, u0; bool lam;
            epilogue_row(h4e, rv.x, rv.y, z0, z1, lse, wL, u0, lam);
            ((float2*)out)[grow] = make_float2(z0, z1);
            out[(size_t)2*NTOT + grow] = lse;
        }
        __syncthreads();
    }
}

extern "C" void kernel_launch(void* const* d_in, const int* in_sizes, int n_in,
                              void* d_out, int out_size, void* d_ws, size_t ws_size,
                              hipStream_t stream) {
    const float* cond = (const float*)d_in[0];
    const float* rnd  = (const float*)d_in[1];
    const float* W0 = (const float*)d_in[2];  const float* b0 = (const float*)d_in[3];
    const float* W1 = (const float*)d_in[4];  const float* b1 = (const float*)d_in[5];
    const float* W2 = (const float*)d_in[6];  const float* b2 = (const float*)d_in[7];
    const float* W3 = (const float*)d_in[8];  const float* b3 = (const float*)d_in[9];
    const float* W4 = (const float*)d_in[10]; const float* b4 = (const float*)d_in[11];
    float* out = (float*)d_out;
    unsigned short* ws = (unsigned short*)d_ws;

    hipLaunchKernelGGL(prep_weights, dim3(544), dim3(256), 0, stream, W0, W1, W2, ws);

    dim3 grid(NTOT / BROWS);
    dim3 block(THREADS);
    size_t shmem = 139264 + 4 + 512;
    hipLaunchKernelGGL(gmm_mfma, grid, block, shmem, stream,
                       cond, rnd, ws, W0, b0, W1, b1, W2, b2, W3, b3, W4, b4, out);
}

// Round 8
// 1450.716 us; speedup vs baseline: 2.4670x; 2.4670x over previous
//
#include <hip/hip_runtime.h>
#include <math.h>

#define NTOT 262144
#define BROWS 128
#define THREADS 512

typedef short bf16x8 __attribute__((ext_vector_type(8)));
typedef float f32x16 __attribute__((ext_vector_type(16)));

// ws u16 offsets (pre-split transposed weights Wt[n][k], k contiguous)
#define O0H 0
#define O0L 8192
#define O1H 16384
#define O1L 81920
#define O2H 147456
#define O2L 212992

__device__ __forceinline__ unsigned short bf16_rne(float x){
    unsigned u = __float_as_uint(x);
    return (unsigned short)((u + 0x7FFFu + ((u >> 16) & 1u)) >> 16);
}
__device__ __forceinline__ void split2(float x, unsigned short& h, unsigned short& l){
    h = bf16_rne(x);
    float xh = __uint_as_float(((unsigned)h) << 16);
    l = bf16_rne(x - xh);
}

__global__ void prep_weights(const float* __restrict__ W0, const float* __restrict__ W1,
                             const float* __restrict__ W2, unsigned short* __restrict__ ws){
    int i = blockIdx.x * 256 + threadIdx.x;
    float v; int oh, ol;
    if (i < 8192){        int n = i >> 6, k = i & 63;                 v = W0[k*128 + n]; oh = O0H + i; ol = O0L + i; }
    else if (i < 73728){  int j = i - 8192;  int n = j >> 7, k = j & 127; v = W1[k*512 + n]; oh = O1H + j; ol = O1L + j; }
    else if (i < 139264){ int j = i - 73728; int n = j >> 9, k = j & 511; v = W2[k*128 + n]; oh = O2H + j; ol = O2L + j; }
    else return;
    unsigned short h, l; split2(v, h, l);
    ws[oh] = h; ws[ol] = l;
}

__device__ __forceinline__ void epilogue_row(const float* __restrict__ h, float r0v, float r1v,
        float& z0o, float& z1o, float& lseo, float& wLo, float& u0o, bool& lamo){
    float wraw[9]; float wsum = 0.0f;
    #pragma unroll
    for (int j = 0; j < 9; ++j){ wraw[j] = fabsf(h[32 + j]); wsum += wraw[j]; }
    float wL = wraw[8] / wsum;
    const bool lambert = r0v < wL;
    float u0 = lambert ? (r0v / wL) : ((r0v - wL) / (1.0f - wL));
    float U1 = lambert ? 0.5f : u0;
    U1 = fmaxf(U1, 1e-12f);
    float R  = sqrtf(-2.0f * logf(U1));
    float th = 6.28318530717958647692f * r1v;
    float ce = cosf(th), se = sinf(th);
    float es0[8], es1[8];
    float ssum0 = 0.0f, ssum1 = 0.0f, lsum0 = 0.0f, lsum1 = 0.0f;
    #pragma unroll
    for (int m = 0; m < 8; ++m){
        es0[m] = expf(h[16 + 2*m]); es1[m] = expf(h[16 + 2*m + 1]);
        ssum0 += es0[m]; ssum1 += es1[m];
        lsum0 += h[2*m]; lsum1 += h[2*m + 1];
    }
    float zg0 = (R * ce) * ssum0 + lsum0;
    float zg1 = (R * se) * ssum1 + lsum1;
    float wo0 = u0 * 2.0f - 1.0f;
    float wo1 = r1v * 2.0f - 1.0f;
    bool nonzero = !((wo0 == 0.0f) && (wo1 == 0.0f));
    bool c1 = (fabsf(wo0) > fabsf(wo1)) && nonzero;
    bool c2 = (!c1) && nonzero;
    float sa0 = (wo0 == 0.0f) ? 1.0f : wo0;
    float sa1 = (wo1 == 0.0f) ? 1.0f : wo1;
    float phi = c1 ? (0.78539816339f * wo1 / sa0)
                   : (1.57079632679f - 0.78539816339f * wo0 / sa1);
    float rr = c1 ? wo0 : (c2 ? wo1 : 0.0f);
    float zl0 = rr * cosf(phi);
    float zl1 = rr * sinf(phi);
    float z0 = lambert ? zl0 : zg0;
    float z1 = lambert ? zl1 : zg1;
    float lp[9];
    #pragma unroll
    for (int m = 0; m < 8; ++m){
        float e0 = (z0 - h[2*m])     / es0[m];
        float e1 = (z1 - h[2*m + 1]) / es1[m];
        float wm = wraw[m] / wsum;
        lp[m] = (-1.83787706640934548356f + logf(wm + 1e-5f))
                - 0.5f * (e0*e0 + e1*e1)
                - (h[16 + 2*m] + h[16 + 2*m + 1]);
    }
    float pdf = (z0*z0 + z1*z1 > 1.0f) ? 0.0f : 0.31830988618f;
    lp[8] = logf(pdf + 1e-5f) + logf(wL);
    float mx = lp[0];
    #pragma unroll
    for (int j = 1; j < 9; ++j) mx = fmaxf(mx, lp[j]);
    float s = 0.0f;
    #pragma unroll
    for (int j = 0; j < 9; ++j) s += expf(lp[j] - mx);
    z0o = z0; z1o = z1; lseo = mx + logf(s); wLo = wL; u0o = u0; lamo = lambert;
}

__device__ __forceinline__ f32x16 bias_init(const float* __restrict__ b, int mt, int lane, int nmax){
    f32x16 c;
    const int hq = ((lane >> 5) << 2);
    #pragma unroll
    for (int r = 0; r < 16; ++r){
        int n = mt + (r & 3) + ((r >> 2) << 3) + hq;
        c[r] = (n < nmax) ? b[n] : 0.0f;
    }
    return c;
}

__device__ __forceinline__ void write_tile(unsigned short* __restrict__ ah, unsigned short* __restrict__ al,
        int pitch, int brow, int m0, int lane, const f32x16 acc, bool relu){
    const int hq = ((lane >> 5) << 2);
    #pragma unroll
    for (int q = 0; q < 4; ++q){
        ushort4 vh, vl;
        #pragma unroll
        for (int r = 0; r < 4; ++r){
            float x = acc[q*4 + r];
            if (relu) x = fmaxf(x, 0.0f);
            unsigned short hh, ll; split2(x, hh, ll);
            (&vh.x)[r] = hh; (&vl.x)[r] = ll;
        }
        const int off = brow*pitch + m0 + q*8 + hq;
        *(ushort4*)(ah + off) = vh;
        *(ushort4*)(al + off) = vl;
    }
}

__device__ __forceinline__ void write_tile_f32t(float* __restrict__ dst,
        int brow, int m0, int lane, const f32x16 acc){
    const int hq = ((lane >> 5) << 2);
    #pragma unroll
    for (int q = 0; q < 4; ++q){
        #pragma unroll
        for (int r = 0; r < 4; ++r){
            int n = m0 + q*8 + hq + r;
            dst[n*128 + brow] = fmaxf(acc[q*4 + r], 0.0f);
        }
    }
}

// D = Wt . act over NK k-steps of 16; unroll limited to 2 to bound VGPR pressure (spill fix)
template<int NK, int KP, int T>
__device__ __forceinline__ void gemm_phase(
        const unsigned short* __restrict__ wth, const unsigned short* __restrict__ wtl,
        const unsigned short* __restrict__ acth, const unsigned short* __restrict__ actl,
        int pitch, int brow, int m0, int lane, f32x16* acc){
    const int kl = ((lane >> 5) << 3);
    const int ml = lane & 31;
    #pragma unroll 2
    for (int ks = 0; ks < NK; ++ks){
        const int k0 = ks*16 + kl;
        bf16x8 ah = *(const bf16x8*)(acth + brow*pitch + k0);
        bf16x8 al = *(const bf16x8*)(actl + brow*pitch + k0);
        #pragma unroll
        for (int t = 0; t < T; ++t){
            const size_t wo = (size_t)(m0 + t*32 + ml) * KP + k0;
            bf16x8 wh = *(const bf16x8*)(wth + wo);
            bf16x8 wl = *(const bf16x8*)(wtl + wo);
            acc[t] = __builtin_amdgcn_mfma_f32_32x32x16_bf16(wh, ah, acc[t], 0, 0, 0);
            acc[t] = __builtin_amdgcn_mfma_f32_32x32x16_bf16(wh, al, acc[t], 0, 0, 0);
            acc[t] = __builtin_amdgcn_mfma_f32_32x32x16_bf16(wl, ah, acc[t], 0, 0, 0);
        }
    }
}

__global__ __launch_bounds__(THREADS, 2)
void gmm_mfma(const float* __restrict__ cond, const float* __restrict__ rnd,
              const unsigned short* __restrict__ ws,
              const float* __restrict__ W0, const float* __restrict__ b0,
              const float* __restrict__ W1, const float* __restrict__ b1,
              const float* __restrict__ W2, const float* __restrict__ b2,
              const float* __restrict__ W3, const float* __restrict__ b3,
              const float* __restrict__ W4, const float* __restrict__ b4,
              float* __restrict__ out)
{
    extern __shared__ unsigned char smem[];
    unsigned short* aAh = (unsigned short*)smem;         // [128][136] split h0
    unsigned short* aAl = aAh + 128*136;
    unsigned short* aBh = aAl + 128*136;                 // [128][136] split h1 chunk
    unsigned short* aBl = aBh + 128*136;
    float* h2f = (float*)smem;                           // [128 n][128 row] overlays aA after use
    float* h3f = (float*)(smem + 69632);                 // [32 n][128 row] overlays aB
    float* h4f = (float*)(smem + 86016);                 // [44 n][128 row]
    int* s_cnt  = (int*)(smem + 139264);
    int* s_rows = (int*)(smem + 139268);                 // 128 ints
    float* fb = (float*)smem;                            // fallback scratch (overlays h2f)

    const int tid  = threadIdx.x;
    const int lane = tid & 63;
    const int wv   = tid >> 6;
    const int row0 = blockIdx.x * BROWS;
    const int rg   = wv & 3;
    const int ctp  = wv >> 2;            // 0/1
    const int brow = rg*32 + (lane & 31);
    const int m0   = ctp * 64;
    const int kl   = ((lane >> 5) << 3);
    const int ml   = lane & 31;

    // ---- L0: h0 = relu(cond @ W0) ----
    {
        f32x16 acc0 = bias_init(b0, m0,      lane, 128);
        f32x16 acc1 = bias_init(b0, m0 + 32, lane, 128);
        #pragma unroll 2
        for (int ks = 0; ks < 4; ++ks){
            const int k0 = ks*16 + kl;
            const float* cp = cond + (size_t)(row0 + brow)*64 + k0;
            float4 ca = *(const float4*)cp;
            float4 cb = *(const float4*)(cp + 4);
            float xs[8] = {ca.x, ca.y, ca.z, ca.w, cb.x, cb.y, cb.z, cb.w};
            bf16x8 ah, al;
            #pragma unroll
            for (int j = 0; j < 8; ++j){
                unsigned short hh, ll; split2(xs[j], hh, ll);
                ah[j] = (short)hh; al[j] = (short)ll;
            }
            #pragma unroll
            for (int t = 0; t < 2; ++t){
                const size_t wo = (size_t)(m0 + t*32 + ml) * 64 + k0;
                bf16x8 wh = *(const bf16x8*)(ws + O0H + wo);
                bf16x8 wl = *(const bf16x8*)(ws + O0L + wo);
                f32x16& a = t ? acc1 : acc0;
                a = __builtin_amdgcn_mfma_f32_32x32x16_bf16(wh, ah, a, 0, 0, 0);
                a = __builtin_amdgcn_mfma_f32_32x32x16_bf16(wh, al, a, 0, 0, 0);
                a = __builtin_amdgcn_mfma_f32_32x32x16_bf16(wl, ah, a, 0, 0, 0);
            }
        }
        write_tile(aAh, aAl, 136, brow, m0,      lane, acc0, true);
        write_tile(aAh, aAl, 136, brow, m0 + 32, lane, acc1, true);
    }
    __syncthreads();

    // ---- L1 (chunked 128 cols) fused with L2 accumulation ----
    f32x16 acc2[2] = { bias_init(b2, m0, lane, 128), bias_init(b2, m0 + 32, lane, 128) };
    for (int c = 0; c < 4; ++c){
        f32x16 a1[2] = { bias_init(b1 + c*128, m0, lane, 512), bias_init(b1 + c*128, m0 + 32, lane, 512) };
        gemm_phase<8, 128, 2>(ws + O1H + (size_t)(c*128)*128, ws + O1L + (size_t)(c*128)*128,
                              aAh, aAl, 136, brow, m0, lane, a1);
        __syncthreads();
        write_tile(aBh, aBl, 136, brow, m0,      lane, a1[0], true);
        write_tile(aBh, aBl, 136, brow, m0 + 32, lane, a1[1], true);
        __syncthreads();
        gemm_phase<8, 512, 2>(ws + O2H + c*128, ws + O2L + c*128,
                              aBh, aBl, 136, brow, m0, lane, acc2);
    }
    write_tile_f32t(h2f, brow, m0,      lane, acc2[0]);
    write_tile_f32t(h2f, brow, m0 + 32, lane, acc2[1]);
    __syncthreads();

    // ---- L3: 128 -> 32 relu, exact fp32 ----
    {
        const int row = tid & 127;
        const int nb  = __builtin_amdgcn_readfirstlane(tid >> 7);
        float acc[8];
        #pragma unroll
        for (int c = 0; c < 8; ++c) acc[c] = b3[nb*8 + c];
        #pragma unroll 4
        for (int k = 0; k < 128; ++k){
            float a = h2f[k*128 + row];
            const float* wr = W3 + k*32 + nb*8;
            #pragma unroll
            for (int c = 0; c < 8; ++c) acc[c] = fmaf(a, wr[c], acc[c]);
        }
        __syncthreads();
        #pragma unroll
        for (int c = 0; c < 8; ++c) h3f[(nb*8 + c)*128 + row] = fmaxf(acc[c], 0.0f);
    }
    if (tid == 0) *s_cnt = 0;
    __syncthreads();

    // ---- L4: 32 -> 41, exact fp32 ----
    {
        const int row = tid & 127;
        const int nb  = __builtin_amdgcn_readfirstlane(tid >> 7);
        float acc[11];
        #pragma unroll
        for (int c = 0; c < 11; ++c){ int n = nb*11 + c; acc[c] = (n < 41) ? b4[n] : 0.0f; }
        #pragma unroll 4
        for (int k = 0; k < 32; ++k){
            float a = h3f[k*128 + row];
            const float* wr = W4 + k*41;
            #pragma unroll
            for (int c = 0; c < 11; ++c){ int n = nb*11 + c; if (n < 41) acc[c] = fmaf(a, wr[n], acc[c]); }
        }
        #pragma unroll
        for (int c = 0; c < 11; ++c){ int n = nb*11 + c; if (n < 41) h4f[n*128 + row] = acc[c]; }
    }
    __syncthreads();

    // ---- epilogue (approx h) + sensitivity flags ----
    if (tid < 128){
        const int row  = tid;
        const int grow = row0 + row;
        float h[41];
        #pragma unroll
        for (int j = 0; j < 41; ++j) h[j] = h4f[j*128 + row];
        float2 rv = *(const float2*)(rnd + 2*(size_t)grow);
        float z0, z1, lse, wL, u0; bool lam;
        epilogue_row(h, rv.x, rv.y, z0, z1, lse, wL, u0, lam);
        ((float2*)out)[grow] = make_float2(z0, z1);
        out[(size_t)2*NTOT + grow] = lse;
        bool flag = (fabsf(rv.x - wL) < 5e-3f)
                 || (wL < 3e-3f) || (wL > 0.5f)
                 || (fabsf(z0*z0 + z1*z1 - 1.0f) < (lam ? 0.02f : 0.2f))
                 || (!lam && u0 < 3e-3f);
        if (flag){ int idx = atomicAdd(s_cnt, 1); s_rows[idx] = row; }
    }
    __syncthreads();
    const int cnt = *s_cnt;

    // ---- exact fp32 fallback, weights-stationary over groups of <=8 rows ----
    float* c0g = fb;            // [8][64]
    float* f0g = fb + 512;      // [8][128]
    float* f1g = fb + 1536;     // [8][512]
    float* f2g = fb + 5632;     // [8][128]
    float* f3g = fb + 6656;     // [8][32]
    float* h4g = fb + 6912;     // [8][48]
    for (int base = 0; base < cnt; base += 8){
        const int g = min(8, cnt - base);
        {   // load cond rows for the group
            int i = tid >> 6, k = tid & 63;
            if (i < g) c0g[i*64 + k] = cond[(size_t)(row0 + s_rows[base + i])*64 + k];
        }
        __syncthreads();
        if (tid < 128){  // L0
            float acc[8];
            #pragma unroll
            for (int i = 0; i < 8; ++i) acc[i] = b0[tid];
            for (int k = 0; k < 64; ++k){
                float w = W0[k*128 + tid];
                #pragma unroll
                for (int i = 0; i < 8; ++i) acc[i] = fmaf(c0g[i*64 + k], w, acc[i]);
            }
            for (int i = 0; i < g; ++i) f0g[i*128 + tid] = fmaxf(acc[i], 0.0f);
        }
        __syncthreads();
        {   // L1 (all 512 threads)
            float acc[8];
            #pragma unroll
            for (int i = 0; i < 8; ++i) acc[i] = b1[tid];
            for (int k = 0; k < 128; ++k){
                float w = W1[k*512 + tid];
                #pragma unroll
                for (int i = 0; i < 8; ++i) acc[i] = fmaf(f0g[i*128 + k], w, acc[i]);
            }
            for (int i = 0; i < g; ++i) f1g[i*512 + tid] = fmaxf(acc[i], 0.0f);
        }
        __syncthreads();
        if (tid < 128){  // L2
            float acc[8];
            #pragma unroll
            for (int i = 0; i < 8; ++i) acc[i] = b2[tid];
            for (int k = 0; k < 512; ++k){
                float w = W2[k*128 + tid];
                #pragma unroll
                for (int i = 0; i < 8; ++i) acc[i] = fmaf(f1g[i*512 + k], w, acc[i]);
            }
            for (int i = 0; i < g; ++i) f2g[i*128 + tid] = fmaxf(acc[i], 0.0f);
        }
        __syncthreads();
        if (tid < 32){   // L3
            float acc[8];
            #pragma unroll
            for (int i = 0; i < 8; ++i) acc[i] = b3[tid];
            for (int k = 0; k < 128; ++k){
                float w = W3[k*32 + tid];
                #pragma unroll
                for (int i = 0; i < 8; ++i) acc[i] = fmaf(f2g[i*128 + k], w, acc[i]);
            }
            for (int i = 0; i < g; ++i) f3g[i*32 + tid] = fmaxf(acc[i], 0.0f);
        }
        __syncthreads();
        if (tid < 41){   // L4
            float acc[8];
            #pragma unroll
            for (int i = 0; i < 8; ++i) acc[i] = b4[tid];
            for (int k = 0; k < 32; ++k){
                float w = W4[k*41 + tid];
                #pragma unroll
                for (int i = 0; i < 8; ++i) acc[i] = fmaf(f3g[i*32 + k], w, acc[i]);
            }
            for (int i = 0; i < g; ++i) h4g[i*48 + tid] = acc[i];
        }
        __syncthreads();
        if (tid < g){    // per-row epilogue, exact h
            const int grow = row0 + s_rows[base + tid];
            float2 rv = *(const float2*)(rnd + 2*(size_t)grow);
            float z0, z1, lse, wL, u0; bool lam;
            epilogue_row(&h4g[tid*48], rv.x, rv.y, z0, z1, lse, wL, u0, lam);
            ((float2*)out)[grow] = make_float2(z0, z1);
            out[(size_t)2*NTOT + grow] = lse;
        }
        __syncthreads();
    }
}

extern "C" void kernel_launch(void* const* d_in, const int* in_sizes, int n_in,
                              void* d_out, int out_size, void* d_ws, size_t ws_size,
                              hipStream_t stream) {
    const float* cond = (const float*)d_in[0];
    const float* rnd  = (const float*)d_in[1];
    const float* W0 = (const float*)d_in[2];  const float* b0 = (const float*)d_in[3];
    const float* W1 = (const float*)d_in[4];  const float* b1 = (const float*)d_in[5];
    const float* W2 = (const float*)d_in[6];  const float* b2 = (const float*)d_in[7];
    const float* W3 = (const float*)d_in[8];  const float* b3 = (const float*)d_in[9];
    const float* W4 = (const float*)d_in[10]; const float* b4 = (const float*)d_in[11];
    float* out = (float*)d_out;
    unsigned short* ws = (unsigned short*)d_ws;

    hipLaunchKernelGGL(prep_weights, dim3(544), dim3(256), 0, stream, W0, W1, W2, ws);

    dim3 grid(NTOT / BROWS);
    dim3 block(THREADS);
    size_t shmem = 139264 + 4 + 512;
    hipLaunchKernelGGL(gmm_mfma, grid, block, shmem, stream,
                       cond, rnd, ws, W0, b0, W1, b1, W2, b2, W3, b3, W4, b4, out);
}